// Round 2
// baseline (1418.739 us; speedup 1.0000x reference)
//
#include <hip/hip_runtime.h>
#include <cstdint>
#include <cmath>

#define HID 32
#define GATES 96  // 3*HID
#define F 128

// ws layout (floats): xw[N*96] | agg[N*96] | deg[N]

__global__ __launch_bounds__(256) void k_init(float* __restrict__ agg, float* __restrict__ deg, int N) {
    int i = blockIdx.x * blockDim.x + threadIdx.x;
    int total = N * GATES;
    if (i < total) agg[i] = 0.0f;
    if (i < N) deg[i] = 1.0f;   // self-loop weight
}

__global__ __launch_bounds__(256) void k_deg(const int* __restrict__ ei,
                                             const float* __restrict__ w,
                                             float* __restrict__ deg, int E) {
    int e = blockIdx.x * blockDim.x + threadIdx.x;
    if (e >= E) return;
    int d = ei[(size_t)E + e];
    atomicAdd(&deg[d], w[e]);
}

__global__ __launch_bounds__(256) void k_rsqrt(float* __restrict__ deg, int N) {
    int i = blockIdx.x * blockDim.x + threadIdx.x;
    if (i < N) deg[i] = rsqrtf(deg[i]);   // deg >= 1 always (self-loop)
}

// xw[n][c] = sum_k x[n][k] * W{z,r,h}[k][c%32]
#define GR 16  // rows per tile
__global__ __launch_bounds__(256) void k_gemm(const float* __restrict__ x,
        const float* __restrict__ Wz, const float* __restrict__ Wr, const float* __restrict__ Wh,
        float* __restrict__ xw, int N) {
    __shared__ float Wl[F * GATES];      // 49152 B
    __shared__ float xs[GR][F + 1];      // padded: avoid bank conflict
    int tid = threadIdx.x;
    for (int i = tid; i < F * GATES; i += 256) {
        int k = i / GATES, c = i % GATES;
        float v;
        if (c < 32)      v = Wz[k * 32 + c];
        else if (c < 64) v = Wr[k * 32 + (c - 32)];
        else             v = Wh[k * 32 + (c - 64)];
        Wl[i] = v;
    }
    int r_local = tid / 16;   // 0..15
    int cb = tid % 16;        // columns cb*6 .. cb*6+5
    int ntiles = (N + GR - 1) / GR;
    for (int t = blockIdx.x; t < ntiles; t += gridDim.x) {
        int row0 = t * GR;
        __syncthreads();      // xs reuse (also covers initial Wl load)
        for (int i = tid; i < GR * F; i += 256) {
            int r = i / F, k = i % F;
            int g = row0 + r;
            xs[r][k] = (g < N) ? x[(size_t)g * F + k] : 0.0f;
        }
        __syncthreads();
        int grow = row0 + r_local;
        if (grow < N) {
            float acc[6] = {0, 0, 0, 0, 0, 0};
            for (int k = 0; k < F; ++k) {
                float xv = xs[r_local][k];
                const float* wr = &Wl[k * GATES + cb * 6];
                #pragma unroll
                for (int j = 0; j < 6; ++j) acc[j] += xv * wr[j];
            }
            float* o = &xw[(size_t)grow * GATES + cb * 6];
            #pragma unroll
            for (int j = 0; j < 6; ++j) o[j] = acc[j];
        }
    }
}

// one 32-lane group per edge (lane = feature); 3 gathers + 3 atomic scatters of 128B each
__global__ __launch_bounds__(256) void k_scatter(const int* __restrict__ ei,
        const float* __restrict__ w, const float* __restrict__ dinv,
        const float* __restrict__ xw, float* __restrict__ agg, int E) {
    int l = threadIdx.x & 31;
    long long g0 = (long long)blockIdx.x * (blockDim.x / 32) + (threadIdx.x >> 5);
    long long ng = (long long)gridDim.x * (blockDim.x / 32);
    for (long long e = g0; e < E; e += ng) {
        int s = ei[e];
        int d = ei[(size_t)E + e];
        float nw = dinv[s] * dinv[d] * w[e];
        const float* xs = xw + (size_t)s * GATES;
        float* ad = agg + (size_t)d * GATES;
        atomicAdd(&ad[l],      nw * xs[l]);
        atomicAdd(&ad[32 + l], nw * xs[32 + l]);
        atomicAdd(&ad[64 + l], nw * xs[64 + l]);
    }
}

// one 32-lane group per node: GRU cell + relu + linear(32->10) + softmax + H passthrough
__global__ __launch_bounds__(256) void k_node(
        const float* __restrict__ agg, const float* __restrict__ xw,
        const float* __restrict__ dinv, const float* __restrict__ Hin,
        const float* __restrict__ bz, const float* __restrict__ br, const float* __restrict__ bh,
        const float* __restrict__ Lzw, const float* __restrict__ Lzb,
        const float* __restrict__ Lrw, const float* __restrict__ Lrb,
        const float* __restrict__ Lhw, const float* __restrict__ Lhb,
        const float* __restrict__ linw, const float* __restrict__ linb,
        float* __restrict__ out_probs, float* __restrict__ out_H, int N) {
    __shared__ float sLz[64 * 32], sLr[64 * 32], sLh[64 * 32];
    __shared__ float sLin[32 * 10];
    __shared__ float sbz[32], sbr[32], sbh[32], sLzb[32], sLrb[32], sLhb[32], sLinb[10];
    int tid = threadIdx.x;
    for (int i = tid; i < 2048; i += 256) { sLz[i] = Lzw[i]; sLr[i] = Lrw[i]; sLh[i] = Lhw[i]; }
    for (int i = tid; i < 320; i += 256) sLin[i] = linw[i];
    if (tid < 32) {
        sbz[tid] = bz[tid]; sbr[tid] = br[tid]; sbh[tid] = bh[tid];
        sLzb[tid] = Lzb[tid]; sLrb[tid] = Lrb[tid]; sLhb[tid] = Lhb[tid];
    }
    if (tid < 10) sLinb[tid] = linb[tid];
    __syncthreads();
    int l = tid & 31;
    long long g0 = (long long)blockIdx.x * (blockDim.x / 32) + (tid >> 5);
    long long ng = (long long)gridDim.x * (blockDim.x / 32);
    for (long long n = g0; n < N; n += ng) {
        float di = dinv[n];
        float di2 = di * di;
        const float* an = agg + n * GATES;
        const float* xn = xw + n * GATES;
        float gz = an[l]      + di2 * xn[l]      + sbz[l];
        float gr = an[32 + l] + di2 * xn[32 + l] + sbr[l];
        float gh = an[64 + l] + di2 * xn[64 + l] + sbh[l];
        float Hd = Hin[n * HID + l];
        // Z and R
        float az = sLzb[l], ar = sLrb[l];
        #pragma unroll 8
        for (int k = 0; k < 32; ++k) {
            float gzk = __shfl(gz, k, 32);
            float grk = __shfl(gr, k, 32);
            float Hk  = __shfl(Hd, k, 32);
            az += gzk * sLz[k * 32 + l] + Hk * sLz[(32 + k) * 32 + l];
            ar += grk * sLr[k * 32 + l] + Hk * sLr[(32 + k) * 32 + l];
        }
        float Z = 1.0f / (1.0f + __expf(-az));
        float Rg = 1.0f / (1.0f + __expf(-ar));
        float HR = Hd * Rg;
        float ah = sLhb[l];
        #pragma unroll 8
        for (int k = 0; k < 32; ++k) {
            float ghk = __shfl(gh, k, 32);
            float HRk = __shfl(HR, k, 32);
            ah += ghk * sLh[k * 32 + l] + HRk * sLh[(32 + k) * 32 + l];
        }
        float Ht = tanhf(ah);
        float Hn = Z * Hd + (1.0f - Z) * Ht;
        float h = fmaxf(Hn, 0.0f);
        // logits for class l (lanes 0..9)
        float logit = (l < 10) ? sLinb[l] : -INFINITY;
        #pragma unroll 8
        for (int k = 0; k < 32; ++k) {
            float hk = __shfl(h, k, 32);
            if (l < 10) logit += hk * sLin[k * 10 + l];
        }
        // softmax across lanes 0..9 (butterfly within 16-wide partition)
        float m = logit;
        #pragma unroll
        for (int off = 8; off >= 1; off >>= 1) m = fmaxf(m, __shfl_xor(m, off, 16));
        float ex = (l < 10) ? __expf(logit - m) : 0.0f;
        float sum = ex;
        #pragma unroll
        for (int off = 8; off >= 1; off >>= 1) sum += __shfl_xor(sum, off, 16);
        if (l < 10) out_probs[n * 10 + l] = ex / sum;
        out_H[n * HID + l] = Hd;
    }
}

extern "C" void kernel_launch(void* const* d_in, const int* in_sizes, int n_in,
                              void* d_out, int out_size, void* d_ws, size_t ws_size,
                              hipStream_t stream) {
    const float* x    = (const float*)d_in[0];
    const int*   ei   = (const int*)d_in[1];     // int32 in harness, layout [2][E]
    const float* ew   = (const float*)d_in[2];
    const float* H    = (const float*)d_in[3];
    const float* Wz   = (const float*)d_in[4];
    const float* bz   = (const float*)d_in[5];
    const float* Wr   = (const float*)d_in[6];
    const float* br   = (const float*)d_in[7];
    const float* Wh   = (const float*)d_in[8];
    const float* bh   = (const float*)d_in[9];
    const float* Lzw  = (const float*)d_in[10];
    const float* Lzb  = (const float*)d_in[11];
    const float* Lrw  = (const float*)d_in[12];
    const float* Lrb  = (const float*)d_in[13];
    const float* Lhw  = (const float*)d_in[14];
    const float* Lhb  = (const float*)d_in[15];
    const float* linw = (const float*)d_in[16];
    const float* linb = (const float*)d_in[17];

    int N = in_sizes[0] / F;
    int E = in_sizes[2];

    float* ws  = (float*)d_ws;
    float* xw  = ws;
    float* agg = ws + (size_t)N * GATES;
    float* deg = ws + (size_t)2 * N * GATES;

    float* out_probs = (float*)d_out;
    float* out_H     = (float*)d_out + (size_t)N * 10;

    k_init<<<(N * GATES + 255) / 256, 256, 0, stream>>>(agg, deg, N);
    k_deg<<<(E + 255) / 256, 256, 0, stream>>>(ei, ew, deg, E);
    k_rsqrt<<<(N + 255) / 256, 256, 0, stream>>>(deg, N);
    k_gemm<<<2048, 256, 0, stream>>>(x, Wz, Wr, Wh, xw, N);
    k_scatter<<<8192, 256, 0, stream>>>(ei, ew, deg, xw, agg, E);
    k_node<<<4096, 256, 0, stream>>>(agg, xw, deg, H, bz, br, bh,
                                     Lzw, Lzb, Lrw, Lrb, Lhw, Lhb,
                                     linw, linb, out_probs, out_H, N);
}

// Round 3
// 884.782 us; speedup vs baseline: 1.6035x; 1.6035x over previous
//
#include <hip/hip_runtime.h>
#include <cstdint>
#include <cmath>

#define HID 32
#define GATES 96  // 3*HID
#define F 128
#define CHUNK 256

// ws layout (floats): xw[N*96] | sorted[E*2] | deg[N] | cnt[N] | off[N] | pos[N] | csum[nchunk]

__global__ __launch_bounds__(256) void k_setup(float* __restrict__ deg, unsigned* __restrict__ cnt, int N) {
    int i = blockIdx.x * 256 + threadIdx.x;
    if (i < N) { deg[i] = 1.0f; cnt[i] = 0u; }   // deg starts at self-loop weight 1
}

__global__ __launch_bounds__(256) void k_deg_hist(const int* __restrict__ ei_dst,
                                                  const float* __restrict__ w,
                                                  float* __restrict__ deg,
                                                  unsigned* __restrict__ cnt, int E) {
    int e = blockIdx.x * 256 + threadIdx.x;
    if (e >= E) return;
    int d = ei_dst[e];
    atomicAdd(&deg[d], w[e]);
    atomicAdd(&cnt[d], 1u);
}

__global__ __launch_bounds__(256) void k_chunksum(const unsigned* __restrict__ cnt,
                                                  unsigned* __restrict__ csum, int N) {
    __shared__ unsigned s[256];
    int i = blockIdx.x * 256 + threadIdx.x;
    s[threadIdx.x] = (i < N) ? cnt[i] : 0u;
    __syncthreads();
    for (int off = 128; off > 0; off >>= 1) {
        if (threadIdx.x < off) s[threadIdx.x] += s[threadIdx.x + off];
        __syncthreads();
    }
    if (threadIdx.x == 0) csum[blockIdx.x] = s[0];
}

__global__ void k_scanchunks(unsigned* __restrict__ csum, int nc) {
    if (threadIdx.x == 0 && blockIdx.x == 0) {
        unsigned run = 0;
        for (int c = 0; c < nc; ++c) { unsigned t = csum[c]; csum[c] = run; run += t; }
    }
}

__global__ __launch_bounds__(256) void k_scanapply(const unsigned* __restrict__ cnt,
                                                   const unsigned* __restrict__ csum,
                                                   unsigned* __restrict__ off,
                                                   unsigned* __restrict__ pos, int N) {
    __shared__ unsigned s[2][256];
    int t = threadIdx.x, i = blockIdx.x * 256 + t;
    unsigned v = (i < N) ? cnt[i] : 0u;
    int cur = 0;
    s[0][t] = v;
    __syncthreads();
    for (int o = 1; o < 256; o <<= 1) {
        unsigned x = s[cur][t];
        if (t >= o) x += s[cur][t - o];
        s[cur ^ 1][t] = x;
        cur ^= 1;
        __syncthreads();
    }
    unsigned excl = s[cur][t] - v + csum[blockIdx.x];
    if (i < N) { off[i] = excl; pos[i] = excl; }
}

__global__ __launch_bounds__(256) void k_rsqrt(float* __restrict__ deg, int N) {
    int i = blockIdx.x * 256 + threadIdx.x;
    if (i < N) deg[i] = rsqrtf(deg[i]);   // deg >= 1 (self-loop)
}

// xw[n][c] = x[n][:] @ [Wz|Wr|Wh][:, c]
#define GR 16
__global__ __launch_bounds__(256) void k_gemm(const float* __restrict__ x,
        const float* __restrict__ Wz, const float* __restrict__ Wr, const float* __restrict__ Wh,
        float* __restrict__ xw, int N) {
    __shared__ float Wl[F * GATES];
    __shared__ float xs[GR][F + 1];
    int tid = threadIdx.x;
    for (int i = tid; i < F * GATES; i += 256) {
        int k = i / GATES, c = i % GATES;
        float v;
        if (c < 32)      v = Wz[k * 32 + c];
        else if (c < 64) v = Wr[k * 32 + (c - 32)];
        else             v = Wh[k * 32 + (c - 64)];
        Wl[i] = v;
    }
    int r_local = tid / 16;
    int cb = tid % 16;
    int ntiles = (N + GR - 1) / GR;
    for (int t = blockIdx.x; t < ntiles; t += gridDim.x) {
        int row0 = t * GR;
        __syncthreads();
        for (int i = tid; i < GR * F; i += 256) {
            int r = i / F, k = i % F;
            int g = row0 + r;
            xs[r][k] = (g < N) ? x[(size_t)g * F + k] : 0.0f;
        }
        __syncthreads();
        int grow = row0 + r_local;
        if (grow < N) {
            float acc[6] = {0, 0, 0, 0, 0, 0};
            for (int k = 0; k < F; ++k) {
                float xv = xs[r_local][k];
                const float* wr = &Wl[k * GATES + cb * 6];
                #pragma unroll
                for (int j = 0; j < 6; ++j) acc[j] += xv * wr[j];
            }
            float* o = &xw[(size_t)grow * GATES + cb * 6];
            #pragma unroll
            for (int j = 0; j < 6; ++j) o[j] = acc[j];
        }
    }
}

__global__ __launch_bounds__(256) void k_permute(const int* __restrict__ ei,
        const float* __restrict__ w, const float* __restrict__ dinv,
        unsigned* __restrict__ pos, float2* __restrict__ sorted, int E) {
    int e = blockIdx.x * 256 + threadIdx.x;
    if (e >= E) return;
    int s = ei[e];
    int d = ei[(size_t)E + e];
    float nw = dinv[s] * dinv[d] * w[e];
    unsigned p = atomicAdd(&pos[d], 1u);
    sorted[p] = make_float2(__int_as_float(s), nw);
}

// one 32-lane group per dst node: segmented gather-reduce + GRU + relu + linear + softmax
__global__ __launch_bounds__(256) void k_fused(
        const unsigned* __restrict__ off, const unsigned* __restrict__ cnt,
        const float2* __restrict__ sorted,
        const float* __restrict__ xw, const float* __restrict__ dinv, const float* __restrict__ Hin,
        const float* __restrict__ bz, const float* __restrict__ br, const float* __restrict__ bh,
        const float* __restrict__ Lzw, const float* __restrict__ Lzb,
        const float* __restrict__ Lrw, const float* __restrict__ Lrb,
        const float* __restrict__ Lhw, const float* __restrict__ Lhb,
        const float* __restrict__ linw, const float* __restrict__ linb,
        float* __restrict__ out_probs, float* __restrict__ out_H, int N) {
    __shared__ float sLz[64 * 32], sLr[64 * 32], sLh[64 * 32];
    __shared__ float sLin[32 * 10];
    __shared__ float sbz[32], sbr[32], sbh[32], sLzb[32], sLrb[32], sLhb[32], sLinb[10];
    int tid = threadIdx.x;
    for (int i = tid; i < 2048; i += 256) { sLz[i] = Lzw[i]; sLr[i] = Lrw[i]; sLh[i] = Lhw[i]; }
    for (int i = tid; i < 320; i += 256) sLin[i] = linw[i];
    if (tid < 32) {
        sbz[tid] = bz[tid]; sbr[tid] = br[tid]; sbh[tid] = bh[tid];
        sLzb[tid] = Lzb[tid]; sLrb[tid] = Lrb[tid]; sLhb[tid] = Lhb[tid];
    }
    if (tid < 10) sLinb[tid] = linb[tid];
    __syncthreads();
    int l = tid & 31;
    int n = blockIdx.x * 8 + (tid >> 5);
    if (n >= N) return;

    float di = dinv[n];
    float di2 = di * di;
    const float* xn = xw + (size_t)n * GATES;
    float a0 = di2 * xn[l];
    float a1 = di2 * xn[32 + l];
    float a2 = di2 * xn[64 + l];

    unsigned base = off[n], len = cnt[n];
    for (unsigned i0 = 0; i0 < len; i0 += 32) {
        int rem = (int)(len - i0);
        int take = rem < 32 ? rem : 32;
        float2 ev = make_float2(0.0f, 0.0f);
        if (l < take) ev = sorted[base + i0 + l];
        for (int j = 0; j < take; ++j) {
            int s    = __shfl(__float_as_int(ev.x), j, 32);
            float nw = __shfl(ev.y, j, 32);
            const float* xs = xw + (size_t)s * GATES;
            a0 += nw * xs[l];
            a1 += nw * xs[32 + l];
            a2 += nw * xs[64 + l];
        }
    }

    float gz = a0 + sbz[l];
    float gr = a1 + sbr[l];
    float gh = a2 + sbh[l];
    float Hd = Hin[(size_t)n * HID + l];

    float az = sLzb[l], ar = sLrb[l];
    #pragma unroll 8
    for (int k = 0; k < 32; ++k) {
        float gzk = __shfl(gz, k, 32);
        float grk = __shfl(gr, k, 32);
        float Hk  = __shfl(Hd, k, 32);
        az += gzk * sLz[k * 32 + l] + Hk * sLz[(32 + k) * 32 + l];
        ar += grk * sLr[k * 32 + l] + Hk * sLr[(32 + k) * 32 + l];
    }
    float Z  = 1.0f / (1.0f + __expf(-az));
    float Rg = 1.0f / (1.0f + __expf(-ar));
    float HR = Hd * Rg;
    float ah = sLhb[l];
    #pragma unroll 8
    for (int k = 0; k < 32; ++k) {
        float ghk = __shfl(gh, k, 32);
        float HRk = __shfl(HR, k, 32);
        ah += ghk * sLh[k * 32 + l] + HRk * sLh[(32 + k) * 32 + l];
    }
    float Ht = tanhf(ah);
    float Hn = Z * Hd + (1.0f - Z) * Ht;
    float h = fmaxf(Hn, 0.0f);

    float logit = (l < 10) ? sLinb[l] : -INFINITY;
    #pragma unroll 8
    for (int k = 0; k < 32; ++k) {
        float hk = __shfl(h, k, 32);
        if (l < 10) logit += hk * sLin[k * 10 + l];
    }
    float m = logit;
    #pragma unroll
    for (int o = 8; o >= 1; o >>= 1) m = fmaxf(m, __shfl_xor(m, o, 16));
    float ex = (l < 10) ? __expf(logit - m) : 0.0f;
    float sum = ex;
    #pragma unroll
    for (int o = 8; o >= 1; o >>= 1) sum += __shfl_xor(sum, o, 16);
    if (l < 10) out_probs[(size_t)n * 10 + l] = ex / sum;
    out_H[(size_t)n * HID + l] = Hd;
}

extern "C" void kernel_launch(void* const* d_in, const int* in_sizes, int n_in,
                              void* d_out, int out_size, void* d_ws, size_t ws_size,
                              hipStream_t stream) {
    const float* x    = (const float*)d_in[0];
    const int*   ei   = (const int*)d_in[1];     // int32, layout [2][E]
    const float* ew   = (const float*)d_in[2];
    const float* H    = (const float*)d_in[3];
    const float* Wz   = (const float*)d_in[4];
    const float* bz   = (const float*)d_in[5];
    const float* Wr   = (const float*)d_in[6];
    const float* br   = (const float*)d_in[7];
    const float* Wh   = (const float*)d_in[8];
    const float* bh   = (const float*)d_in[9];
    const float* Lzw  = (const float*)d_in[10];
    const float* Lzb  = (const float*)d_in[11];
    const float* Lrw  = (const float*)d_in[12];
    const float* Lrb  = (const float*)d_in[13];
    const float* Lhw  = (const float*)d_in[14];
    const float* Lhb  = (const float*)d_in[15];
    const float* linw = (const float*)d_in[16];
    const float* linb = (const float*)d_in[17];

    int N = in_sizes[0] / F;
    int E = in_sizes[2];
    int nchunk = (N + CHUNK - 1) / CHUNK;

    float* ws = (float*)d_ws;
    float*    xw     = ws;
    float2*   sorted = (float2*)(ws + (size_t)N * GATES);
    float*    deg    = ws + (size_t)N * GATES + (size_t)E * 2;
    unsigned* cnt    = (unsigned*)(deg + N);
    unsigned* off    = cnt + N;
    unsigned* pos    = off + N;
    unsigned* csum   = pos + N;

    float* out_probs = (float*)d_out;
    float* out_H     = (float*)d_out + (size_t)N * 10;

    k_setup<<<(N + 255) / 256, 256, 0, stream>>>(deg, cnt, N);
    k_deg_hist<<<(E + 255) / 256, 256, 0, stream>>>(ei + (size_t)E, ew, deg, cnt, E);
    k_chunksum<<<nchunk, 256, 0, stream>>>(cnt, csum, N);
    k_scanchunks<<<1, 64, 0, stream>>>(csum, nchunk);
    k_scanapply<<<nchunk, 256, 0, stream>>>(cnt, csum, off, pos, N);
    k_rsqrt<<<(N + 255) / 256, 256, 0, stream>>>(deg, N);
    k_gemm<<<2048, 256, 0, stream>>>(x, Wz, Wr, Wh, xw, N);
    k_permute<<<(E + 255) / 256, 256, 0, stream>>>(ei, ew, deg, pos, sorted, E);
    k_fused<<<(N + 7) / 8, 256, 0, stream>>>(off, cnt, sorted, xw, deg, H,
                                             bz, br, bh, Lzw, Lzb, Lrw, Lrb, Lhw, Lhb,
                                             linw, linb, out_probs, out_H, N);
}

// Round 5
// 818.938 us; speedup vs baseline: 1.7324x; 1.0804x over previous
//
#include <hip/hip_runtime.h>
#include <cstdint>
#include <cmath>

#define HID 32
#define GATES 96  // 3*HID
#define F 128
#define CHUNK 256

typedef float nfloat2 __attribute__((ext_vector_type(2)));

// ws layout (floats): xw[N*96] | sorted[E*2] | deg[N] | cnt[N] | off[N] | pos[N] | csum[nchunk]

__global__ __launch_bounds__(256) void k_setup(float* __restrict__ deg, unsigned* __restrict__ cnt, int N) {
    int i = blockIdx.x * 256 + threadIdx.x;
    if (i < N) { deg[i] = 1.0f; cnt[i] = 0u; }   // deg starts at self-loop weight 1
}

__global__ __launch_bounds__(256) void k_deg_hist(const int* __restrict__ ei_dst,
                                                  const float* __restrict__ w,
                                                  float* __restrict__ deg,
                                                  unsigned* __restrict__ cnt, int E) {
    int e = blockIdx.x * 256 + threadIdx.x;
    if (e >= E) return;
    int d = ei_dst[e];
    atomicAdd(&deg[d], w[e]);
    atomicAdd(&cnt[d], 1u);
}

__global__ __launch_bounds__(256) void k_chunksum(const unsigned* __restrict__ cnt,
                                                  unsigned* __restrict__ csum, int N) {
    __shared__ unsigned s[256];
    int i = blockIdx.x * 256 + threadIdx.x;
    s[threadIdx.x] = (i < N) ? cnt[i] : 0u;
    __syncthreads();
    for (int off = 128; off > 0; off >>= 1) {
        if (threadIdx.x < off) s[threadIdx.x] += s[threadIdx.x + off];
        __syncthreads();
    }
    if (threadIdx.x == 0) csum[blockIdx.x] = s[0];
}

// parallel exclusive scan over nc (<=1024) chunk sums, single block
__global__ __launch_bounds__(1024) void k_scanchunks(unsigned* __restrict__ csum, int nc) {
    __shared__ unsigned s[1024];
    int t = threadIdx.x;
    unsigned v = (t < nc) ? csum[t] : 0u;
    s[t] = v;
    __syncthreads();
    for (int o = 1; o < 1024; o <<= 1) {
        unsigned x = s[t];
        if (t >= o) x += s[t - o];
        __syncthreads();
        s[t] = x;
        __syncthreads();
    }
    if (t < nc) csum[t] = s[t] - v;   // exclusive
}

__global__ __launch_bounds__(256) void k_scanapply(const unsigned* __restrict__ cnt,
                                                   const unsigned* __restrict__ csum,
                                                   unsigned* __restrict__ off,
                                                   unsigned* __restrict__ pos, int N) {
    __shared__ unsigned s[2][256];
    int t = threadIdx.x, i = blockIdx.x * 256 + t;
    unsigned v = (i < N) ? cnt[i] : 0u;
    int cur = 0;
    s[0][t] = v;
    __syncthreads();
    for (int o = 1; o < 256; o <<= 1) {
        unsigned x = s[cur][t];
        if (t >= o) x += s[cur][t - o];
        s[cur ^ 1][t] = x;
        cur ^= 1;
        __syncthreads();
    }
    unsigned excl = s[cur][t] - v + csum[blockIdx.x];
    if (i < N) { off[i] = excl; pos[i] = excl; }
}

__global__ __launch_bounds__(256) void k_rsqrt(float* __restrict__ deg, int N) {
    int i = blockIdx.x * 256 + threadIdx.x;
    if (i < N) deg[i] = rsqrtf(deg[i]);   // deg >= 1 (self-loop)
}

// xw[n][c] = x[n][:] @ [Wz|Wr|Wh][:, c]
#define GR 16
__global__ __launch_bounds__(256) void k_gemm(const float* __restrict__ x,
        const float* __restrict__ Wz, const float* __restrict__ Wr, const float* __restrict__ Wh,
        float* __restrict__ xw, int N) {
    __shared__ float Wl[F * GATES];
    __shared__ float xs[GR][F + 1];
    int tid = threadIdx.x;
    for (int i = tid; i < F * GATES; i += 256) {
        int k = i / GATES, c = i % GATES;
        float v;
        if (c < 32)      v = Wz[k * 32 + c];
        else if (c < 64) v = Wr[k * 32 + (c - 32)];
        else             v = Wh[k * 32 + (c - 64)];
        Wl[i] = v;
    }
    int r_local = tid / 16;
    int cb = tid % 16;
    int ntiles = (N + GR - 1) / GR;
    for (int t = blockIdx.x; t < ntiles; t += gridDim.x) {
        int row0 = t * GR;
        __syncthreads();
        for (int i = tid; i < GR * F; i += 256) {
            int r = i / F, k = i % F;
            int g = row0 + r;
            xs[r][k] = (g < N) ? x[(size_t)g * F + k] : 0.0f;
        }
        __syncthreads();
        int grow = row0 + r_local;
        if (grow < N) {
            float acc[6] = {0, 0, 0, 0, 0, 0};
            for (int k = 0; k < F; ++k) {
                float xv = xs[r_local][k];
                const float* wr = &Wl[k * GATES + cb * 6];
                #pragma unroll
                for (int j = 0; j < 6; ++j) acc[j] += xv * wr[j];
            }
            float* o = &xw[(size_t)grow * GATES + cb * 6];
            #pragma unroll
            for (int j = 0; j < 6; ++j) o[j] = acc[j];
        }
    }
}

__global__ __launch_bounds__(256) void k_permute(const int* __restrict__ ei,
        const float* __restrict__ w, const float* __restrict__ dinv,
        unsigned* __restrict__ pos, float2* __restrict__ sorted, int E) {
    int e = blockIdx.x * 256 + threadIdx.x;
    if (e >= E) return;
    int s = ei[e];
    int d = ei[(size_t)E + e];
    float nw = dinv[s] * dinv[d] * w[e];
    unsigned p = atomicAdd(&pos[d], 1u);
    sorted[p] = make_float2(__int_as_float(s), nw);
}

// one 32-lane group per dst node: segmented gather-reduce + GRU + relu + linear + softmax.
// NO LDS: GRU weights are broadcast-coalesced loads, L1-resident (25.6 KB total).
__global__ __launch_bounds__(256, 8) void k_fused(
        const unsigned* __restrict__ off, const unsigned* __restrict__ cnt,
        const float2* __restrict__ sorted,
        const float* __restrict__ xw, const float* __restrict__ dinv, const float* __restrict__ Hin,
        const float* __restrict__ bz, const float* __restrict__ br, const float* __restrict__ bh,
        const float* __restrict__ Lzw, const float* __restrict__ Lzb,
        const float* __restrict__ Lrw, const float* __restrict__ Lrb,
        const float* __restrict__ Lhw, const float* __restrict__ Lhb,
        const float* __restrict__ linw, const float* __restrict__ linb,
        float* __restrict__ out_probs, float* __restrict__ out_H, int N) {
    int tid = threadIdx.x;
    int l = tid & 31;
    int n = blockIdx.x * 8 + (tid >> 5);
    if (n >= N) return;

    float di = dinv[n];
    float di2 = di * di;
    const float* xn = xw + (size_t)n * GATES;
    float a0 = di2 * xn[l]      + bz[l];
    float a1 = di2 * xn[32 + l] + br[l];
    float a2 = di2 * xn[64 + l] + bh[l];

    unsigned base = off[n], len = cnt[n];
    for (unsigned i0 = 0; i0 < len; i0 += 32) {
        unsigned rem = len - i0;
        int take = rem < 32u ? (int)rem : 32;
        nfloat2 ev = {0.0f, 0.0f};
        if (l < take)
            ev = __builtin_nontemporal_load((const nfloat2*)sorted + base + i0 + l);
        // software-pipelined: src pointer for j known one iteration ahead
        int   sj  = __shfl(__float_as_int(ev.x), 0, 32);
        float nwj = __shfl(ev.y, 0, 32);
        for (int j = 0; j < take; ++j) {
            const float* p = xw + (size_t)sj * GATES;
            float nw = nwj;
            int jn = (j + 1) & 31;
            sj  = __shfl(__float_as_int(ev.x), jn, 32);
            nwj = __shfl(ev.y, jn, 32);
            a0 += nw * p[l];
            a1 += nw * p[32 + l];
            a2 += nw * p[64 + l];
        }
    }

    float gz = a0;
    float gr = a1;
    float gh = a2;
    float Hd = Hin[(size_t)n * HID + l];

    float az = Lzb[l], ar = Lrb[l];
    #pragma unroll 4
    for (int k = 0; k < 32; ++k) {
        float gzk = __shfl(gz, k, 32);
        float grk = __shfl(gr, k, 32);
        float Hk  = __shfl(Hd, k, 32);
        az += gzk * Lzw[k * 32 + l] + Hk * Lzw[(32 + k) * 32 + l];
        ar += grk * Lrw[k * 32 + l] + Hk * Lrw[(32 + k) * 32 + l];
    }
    float Z  = 1.0f / (1.0f + __expf(-az));
    float Rg = 1.0f / (1.0f + __expf(-ar));
    float HR = Hd * Rg;
    float ah = Lhb[l];
    #pragma unroll 4
    for (int k = 0; k < 32; ++k) {
        float ghk = __shfl(gh, k, 32);
        float HRk = __shfl(HR, k, 32);
        ah += ghk * Lhw[k * 32 + l] + HRk * Lhw[(32 + k) * 32 + l];
    }
    float Ht = tanhf(ah);
    float Hn = Z * Hd + (1.0f - Z) * Ht;
    float h = fmaxf(Hn, 0.0f);

    float logit = (l < 10) ? linb[l] : -INFINITY;
    #pragma unroll 4
    for (int k = 0; k < 32; ++k) {
        float hk = __shfl(h, k, 32);
        if (l < 10) logit += hk * linw[k * 10 + l];
    }
    float m = logit;
    #pragma unroll
    for (int o = 8; o >= 1; o >>= 1) m = fmaxf(m, __shfl_xor(m, o, 16));
    float ex = (l < 10) ? __expf(logit - m) : 0.0f;
    float sum = ex;
    #pragma unroll
    for (int o = 8; o >= 1; o >>= 1) sum += __shfl_xor(sum, o, 16);
    if (l < 10) out_probs[(size_t)n * 10 + l] = ex / sum;
    out_H[(size_t)n * HID + l] = Hd;
}

extern "C" void kernel_launch(void* const* d_in, const int* in_sizes, int n_in,
                              void* d_out, int out_size, void* d_ws, size_t ws_size,
                              hipStream_t stream) {
    const float* x    = (const float*)d_in[0];
    const int*   ei   = (const int*)d_in[1];     // int32, layout [2][E]
    const float* ew   = (const float*)d_in[2];
    const float* H    = (const float*)d_in[3];
    const float* Wz   = (const float*)d_in[4];
    const float* bz   = (const float*)d_in[5];
    const float* Wr   = (const float*)d_in[6];
    const float* br   = (const float*)d_in[7];
    const float* Wh   = (const float*)d_in[8];
    const float* bh   = (const float*)d_in[9];
    const float* Lzw  = (const float*)d_in[10];
    const float* Lzb  = (const float*)d_in[11];
    const float* Lrw  = (const float*)d_in[12];
    const float* Lrb  = (const float*)d_in[13];
    const float* Lhw  = (const float*)d_in[14];
    const float* Lhb  = (const float*)d_in[15];
    const float* linw = (const float*)d_in[16];
    const float* linb = (const float*)d_in[17];

    int N = in_sizes[0] / F;
    int E = in_sizes[2];
    int nchunk = (N + CHUNK - 1) / CHUNK;   // 391 for N=100k; scan kernel supports <=1024

    float* ws = (float*)d_ws;
    float*    xw     = ws;
    float2*   sorted = (float2*)(ws + (size_t)N * GATES);
    float*    deg    = ws + (size_t)N * GATES + (size_t)E * 2;
    unsigned* cnt    = (unsigned*)(deg + N);
    unsigned* off    = cnt + N;
    unsigned* pos    = off + N;
    unsigned* csum   = pos + N;

    float* out_probs = (float*)d_out;
    float* out_H     = (float*)d_out + (size_t)N * 10;

    k_setup<<<(N + 255) / 256, 256, 0, stream>>>(deg, cnt, N);
    k_deg_hist<<<(E + 255) / 256, 256, 0, stream>>>(ei + (size_t)E, ew, deg, cnt, E);
    k_chunksum<<<nchunk, 256, 0, stream>>>(cnt, csum, N);
    k_scanchunks<<<1, 1024, 0, stream>>>(csum, nchunk);
    k_scanapply<<<nchunk, 256, 0, stream>>>(cnt, csum, off, pos, N);
    k_rsqrt<<<(N + 255) / 256, 256, 0, stream>>>(deg, N);
    k_gemm<<<2048, 256, 0, stream>>>(x, Wz, Wr, Wh, xw, N);
    k_permute<<<(E + 255) / 256, 256, 0, stream>>>(ei, ew, deg, pos, sorted, E);
    k_fused<<<(N + 7) / 8, 256, 0, stream>>>(off, cnt, sorted, xw, deg, H,
                                             bz, br, bh, Lzw, Lzb, Lrw, Lrb, Lhw, Lhb,
                                             linw, linb, out_probs, out_H, N);
}

// Round 6
// 584.007 us; speedup vs baseline: 2.4293x; 1.4023x over previous
//
#include <hip/hip_runtime.h>
#include <cstdint>
#include <cmath>

#define HID 32
#define GATES 96  // 3*HID
#define F 128
#define CHUNK 256

typedef float nfloat2 __attribute__((ext_vector_type(2)));

// ws layout (floats): xw[N*96] | sorted[E*2] | dinv[N] | cnt[N] | off[N] | csum[nchunk]
// rank[E] (u32) OVERLAYS the xw region: rank is consumed by k_permute before k_gemm writes xw.

__global__ __launch_bounds__(256) void k_setup(unsigned* __restrict__ cnt, int N) {
    int i = blockIdx.x * 256 + threadIdx.x;
    if (i < N) cnt[i] = 0u;
}

// E atomics total in the whole pipeline: rank[e] = old count (edge's slot within its dst segment)
__global__ __launch_bounds__(256) void k_hist(const int* __restrict__ ei_dst,
                                              unsigned* __restrict__ cnt,
                                              unsigned* __restrict__ rank, int E) {
    int e = blockIdx.x * 256 + threadIdx.x;
    if (e >= E) return;
    rank[e] = atomicAdd(&cnt[ei_dst[e]], 1u);
}

__global__ __launch_bounds__(256) void k_chunksum(const unsigned* __restrict__ cnt,
                                                  unsigned* __restrict__ csum, int N) {
    __shared__ unsigned s[256];
    int i = blockIdx.x * 256 + threadIdx.x;
    s[threadIdx.x] = (i < N) ? cnt[i] : 0u;
    __syncthreads();
    for (int off = 128; off > 0; off >>= 1) {
        if (threadIdx.x < off) s[threadIdx.x] += s[threadIdx.x + off];
        __syncthreads();
    }
    if (threadIdx.x == 0) csum[blockIdx.x] = s[0];
}

// parallel exclusive scan over nc (<=1024) chunk sums, single block
__global__ __launch_bounds__(1024) void k_scanchunks(unsigned* __restrict__ csum, int nc) {
    __shared__ unsigned s[1024];
    int t = threadIdx.x;
    unsigned v = (t < nc) ? csum[t] : 0u;
    s[t] = v;
    __syncthreads();
    for (int o = 1; o < 1024; o <<= 1) {
        unsigned x = s[t];
        if (t >= o) x += s[t - o];
        __syncthreads();
        s[t] = x;
        __syncthreads();
    }
    if (t < nc) csum[t] = s[t] - v;   // exclusive
}

__global__ __launch_bounds__(256) void k_scanapply(const unsigned* __restrict__ cnt,
                                                   const unsigned* __restrict__ csum,
                                                   unsigned* __restrict__ off, int N) {
    __shared__ unsigned s[2][256];
    int t = threadIdx.x, i = blockIdx.x * 256 + t;
    unsigned v = (i < N) ? cnt[i] : 0u;
    int cur = 0;
    s[0][t] = v;
    __syncthreads();
    for (int o = 1; o < 256; o <<= 1) {
        unsigned x = s[cur][t];
        if (t >= o) x += s[cur][t - o];
        s[cur ^ 1][t] = x;
        cur ^= 1;
        __syncthreads();
    }
    unsigned excl = s[cur][t] - v + csum[blockIdx.x];
    if (i < N) off[i] = excl;
}

// atomic-free permute: slot = off[d] + rank[e]; payload = (src, raw w)
__global__ __launch_bounds__(256) void k_permute(const int* __restrict__ ei,
        const float* __restrict__ w, const unsigned* __restrict__ off,
        const unsigned* __restrict__ rank, float2* __restrict__ sorted, int E) {
    int e = blockIdx.x * 256 + threadIdx.x;
    if (e >= E) return;
    int s = ei[e];
    int d = ei[(size_t)E + e];
    unsigned p = off[d] + rank[e];
    sorted[p] = make_float2(__int_as_float(s), w[e]);
}

// dinv[n] = rsqrt(1 + sum of w over CSR segment) — streaming reads, no atomics
__global__ __launch_bounds__(256) void k_degsum(const unsigned* __restrict__ off,
        const unsigned* __restrict__ cnt, const float2* __restrict__ sorted,
        float* __restrict__ dinv, int N) {
    int l = threadIdx.x & 31;
    int n = blockIdx.x * 8 + (threadIdx.x >> 5);
    if (n >= N) return;
    unsigned base = off[n], len = cnt[n];
    float s = 0.0f;
    for (unsigned i = l; i < len; i += 32) s += sorted[base + i].y;
    #pragma unroll
    for (int o = 16; o >= 1; o >>= 1) s += __shfl_xor(s, o, 32);
    if (l == 0) dinv[n] = rsqrtf(1.0f + s);
}

// xw[n][c] = x[n][:] @ [Wz|Wr|Wh][:, c]
#define GR 16
__global__ __launch_bounds__(256) void k_gemm(const float* __restrict__ x,
        const float* __restrict__ Wz, const float* __restrict__ Wr, const float* __restrict__ Wh,
        float* __restrict__ xw, int N) {
    __shared__ float Wl[F * GATES];
    __shared__ float xs[GR][F + 1];
    int tid = threadIdx.x;
    for (int i = tid; i < F * GATES; i += 256) {
        int k = i / GATES, c = i % GATES;
        float v;
        if (c < 32)      v = Wz[k * 32 + c];
        else if (c < 64) v = Wr[k * 32 + (c - 32)];
        else             v = Wh[k * 32 + (c - 64)];
        Wl[i] = v;
    }
    int r_local = tid / 16;
    int cb = tid % 16;
    int ntiles = (N + GR - 1) / GR;
    for (int t = blockIdx.x; t < ntiles; t += gridDim.x) {
        int row0 = t * GR;
        __syncthreads();
        for (int i = tid; i < GR * F; i += 256) {
            int r = i / F, k = i % F;
            int g = row0 + r;
            xs[r][k] = (g < N) ? x[(size_t)g * F + k] : 0.0f;
        }
        __syncthreads();
        int grow = row0 + r_local;
        if (grow < N) {
            float acc[6] = {0, 0, 0, 0, 0, 0};
            for (int k = 0; k < F; ++k) {
                float xv = xs[r_local][k];
                const float* wr = &Wl[k * GATES + cb * 6];
                #pragma unroll
                for (int j = 0; j < 6; ++j) acc[j] += xv * wr[j];
            }
            float* o = &xw[(size_t)grow * GATES + cb * 6];
            #pragma unroll
            for (int j = 0; j < 6; ++j) o[j] = acc[j];
        }
    }
}

// one 32-lane group per dst node: segmented gather-reduce + GRU + relu + linear + softmax.
// NO LDS: GRU weights are broadcast-coalesced loads, L1-resident.
// norm folded: a = di*(sum_edges (w*dinv[s])*xw[s] + di*xn) + b
__global__ __launch_bounds__(256, 8) void k_fused(
        const unsigned* __restrict__ off, const unsigned* __restrict__ cnt,
        const float2* __restrict__ sorted,
        const float* __restrict__ xw, const float* __restrict__ dinv, const float* __restrict__ Hin,
        const float* __restrict__ bz, const float* __restrict__ br, const float* __restrict__ bh,
        const float* __restrict__ Lzw, const float* __restrict__ Lzb,
        const float* __restrict__ Lrw, const float* __restrict__ Lrb,
        const float* __restrict__ Lhw, const float* __restrict__ Lhb,
        const float* __restrict__ linw, const float* __restrict__ linb,
        float* __restrict__ out_probs, float* __restrict__ out_H, int N) {
    int tid = threadIdx.x;
    int l = tid & 31;
    int n = blockIdx.x * 8 + (tid >> 5);
    if (n >= N) return;

    float di = dinv[n];
    const float* xn = xw + (size_t)n * GATES;
    float a0 = di * xn[l];
    float a1 = di * xn[32 + l];
    float a2 = di * xn[64 + l];

    unsigned base = off[n], len = cnt[n];
    for (unsigned i0 = 0; i0 < len; i0 += 32) {
        unsigned rem = len - i0;
        int take = rem < 32u ? (int)rem : 32;
        nfloat2 ev = {0.0f, 0.0f};
        if (l < take)
            ev = __builtin_nontemporal_load((const nfloat2*)sorted + base + i0 + l);
        int   se = __float_as_int(ev.x);          // src (0 for inactive lanes)
        float m  = ev.y * dinv[se];               // w * dinv[src]  (0 for inactive)
        // software-pipelined broadcast
        int   sj = __shfl(se, 0, 32);
        float mj = __shfl(m, 0, 32);
        for (int j = 0; j < take; ++j) {
            const float* p = xw + (size_t)sj * GATES;
            float nw = mj;
            int jn = (j + 1) & 31;
            sj = __shfl(se, jn, 32);
            mj = __shfl(m, jn, 32);
            a0 += nw * p[l];
            a1 += nw * p[32 + l];
            a2 += nw * p[64 + l];
        }
    }

    float gz = di * a0 + bz[l];
    float gr = di * a1 + br[l];
    float gh = di * a2 + bh[l];
    float Hd = Hin[(size_t)n * HID + l];

    float az = Lzb[l], ar = Lrb[l];
    #pragma unroll 4
    for (int k = 0; k < 32; ++k) {
        float gzk = __shfl(gz, k, 32);
        float grk = __shfl(gr, k, 32);
        float Hk  = __shfl(Hd, k, 32);
        az += gzk * Lzw[k * 32 + l] + Hk * Lzw[(32 + k) * 32 + l];
        ar += grk * Lrw[k * 32 + l] + Hk * Lrw[(32 + k) * 32 + l];
    }
    float Z  = 1.0f / (1.0f + __expf(-az));
    float Rg = 1.0f / (1.0f + __expf(-ar));
    float HR = Hd * Rg;
    float ah = Lhb[l];
    #pragma unroll 4
    for (int k = 0; k < 32; ++k) {
        float ghk = __shfl(gh, k, 32);
        float HRk = __shfl(HR, k, 32);
        ah += ghk * Lhw[k * 32 + l] + HRk * Lhw[(32 + k) * 32 + l];
    }
    float Ht = tanhf(ah);
    float Hn = Z * Hd + (1.0f - Z) * Ht;
    float h = fmaxf(Hn, 0.0f);

    float logit = (l < 10) ? linb[l] : -INFINITY;
    #pragma unroll 4
    for (int k = 0; k < 32; ++k) {
        float hk = __shfl(h, k, 32);
        if (l < 10) logit += hk * linw[k * 10 + l];
    }
    float m = logit;
    #pragma unroll
    for (int o = 8; o >= 1; o >>= 1) m = fmaxf(m, __shfl_xor(m, o, 16));
    float ex = (l < 10) ? __expf(logit - m) : 0.0f;
    float sum = ex;
    #pragma unroll
    for (int o = 8; o >= 1; o >>= 1) sum += __shfl_xor(sum, o, 16);
    if (l < 10) out_probs[(size_t)n * 10 + l] = ex / sum;
    out_H[(size_t)n * HID + l] = Hd;
}

extern "C" void kernel_launch(void* const* d_in, const int* in_sizes, int n_in,
                              void* d_out, int out_size, void* d_ws, size_t ws_size,
                              hipStream_t stream) {
    const float* x    = (const float*)d_in[0];
    const int*   ei   = (const int*)d_in[1];     // int32, layout [2][E]
    const float* ew   = (const float*)d_in[2];
    const float* H    = (const float*)d_in[3];
    const float* Wz   = (const float*)d_in[4];
    const float* bz   = (const float*)d_in[5];
    const float* Wr   = (const float*)d_in[6];
    const float* br   = (const float*)d_in[7];
    const float* Wh   = (const float*)d_in[8];
    const float* bh   = (const float*)d_in[9];
    const float* Lzw  = (const float*)d_in[10];
    const float* Lzb  = (const float*)d_in[11];
    const float* Lrw  = (const float*)d_in[12];
    const float* Lrb  = (const float*)d_in[13];
    const float* Lhw  = (const float*)d_in[14];
    const float* Lhb  = (const float*)d_in[15];
    const float* linw = (const float*)d_in[16];
    const float* linb = (const float*)d_in[17];

    int N = in_sizes[0] / F;
    int E = in_sizes[2];
    int nchunk = (N + CHUNK - 1) / CHUNK;   // 391 for N=100k; scan supports <=1024

    float* ws = (float*)d_ws;
    float*    xw     = ws;
    float2*   sorted = (float2*)(ws + (size_t)N * GATES);
    float*    dinv   = ws + (size_t)N * GATES + (size_t)E * 2;
    unsigned* cnt    = (unsigned*)(dinv + N);
    unsigned* off    = cnt + N;
    unsigned* csum   = off + N;
    unsigned* rank   = (unsigned*)xw;   // overlay: dead before k_gemm writes xw

    float* out_probs = (float*)d_out;
    float* out_H     = (float*)d_out + (size_t)N * 10;

    k_setup<<<(N + 255) / 256, 256, 0, stream>>>(cnt, N);
    k_hist<<<(E + 255) / 256, 256, 0, stream>>>(ei + (size_t)E, cnt, rank, E);
    k_chunksum<<<nchunk, 256, 0, stream>>>(cnt, csum, N);
    k_scanchunks<<<1, 1024, 0, stream>>>(csum, nchunk);
    k_scanapply<<<nchunk, 256, 0, stream>>>(cnt, csum, off, N);
    k_permute<<<(E + 255) / 256, 256, 0, stream>>>(ei, ew, off, rank, sorted, E);
    k_degsum<<<(N + 7) / 8, 256, 0, stream>>>(off, cnt, sorted, dinv, N);
    k_gemm<<<2048, 256, 0, stream>>>(x, Wz, Wr, Wh, xw, N);
    k_fused<<<(N + 7) / 8, 256, 0, stream>>>(off, cnt, sorted, xw, dinv, H,
                                             bz, br, bh, Lzw, Lzb, Lrw, Lrb, Lhw, Lhb,
                                             linw, linb, out_probs, out_H, N);
}